// Round 8
// baseline (313.554 us; speedup 1.0000x reference)
//
#include <hip/hip_runtime.h>
#include <hip/hip_bf16.h>

typedef unsigned short ushort_t;
typedef __attribute__((ext_vector_type(8))) short short8;
typedef __attribute__((ext_vector_type(4))) float floatx4;

__device__ __forceinline__ unsigned short f2bf(float f) {
    union { float f; unsigned u; } x; x.f = f;
    unsigned r = x.u + 0x7fffu + ((x.u >> 16) & 1u);  // RNE
    return (unsigned short)(r >> 16);
}
__device__ __forceinline__ float bf2f(unsigned short u) {
    union { unsigned u; float f; } x; x.u = ((unsigned)u) << 16; return x.f;
}
__device__ __forceinline__ float u2f(unsigned u) {
    union { unsigned u; float f; } x; x.u = u; return x.f;
}

// ------------- transpose+convert 128x128 f32 weights -> bf16 Wt[n][k] --------
__global__ __launch_bounds__(256) void transpose128(
    const float* __restrict__ Wq, const float* __restrict__ Wk,
    const float* __restrict__ Wv, const float* __restrict__ Wo,
    ushort_t* __restrict__ out)
{
    const float* W = (blockIdx.y == 0) ? Wq : (blockIdx.y == 1) ? Wk :
                     (blockIdx.y == 2) ? Wv : Wo;
    ushort_t* T = out + (size_t)blockIdx.y * 128 * 128;
    int tr = blockIdx.x >> 2, tc = blockIdx.x & 3;   // 4x4 tiles of 32x32
    __shared__ float s[32][33];
    int tx = threadIdx.x & 31, ty = threadIdx.x >> 5;  // 32 x 8
    for (int j = 0; j < 32; j += 8)
        s[ty + j][tx] = W[(tr * 32 + ty + j) * 128 + tc * 32 + tx];
    __syncthreads();
    for (int j = 0; j < 32; j += 8)
        T[(tc * 32 + ty + j) * 128 + tr * 32 + tx] = f2bf(s[tx][ty + j]);
}

// ------------- QKV GEMM: A in LDS (17.4KB), B register-direct (L1-resident) --
// grid (rows,3). Q -> [M,128] bf16. KV 8-interleaved: row n, col c:
// K at n*256+(c>>3)*16+(c&7), V at +8.  Folded dst-histogram per block.
__global__ __launch_bounds__(256) void gemm_qkv(
    const float* __restrict__ X, const ushort_t* __restrict__ Wt,
    const float* __restrict__ bq, const float* __restrict__ bk, const float* __restrict__ bv,
    ushort_t* __restrict__ Q, ushort_t* __restrict__ KV, int M,
    const int* __restrict__ dst, int* __restrict__ deg, int E)
{
    __shared__ ushort_t Xs[64 * 136];
    int tid = threadIdx.x;
    int rowBase = blockIdx.x * 64;
    int wsel = blockIdx.y;
    const ushort_t* Wmat = Wt + (size_t)wsel * 128 * 128;  // [n][k]
    const float* bias = (wsel == 0) ? bq : (wsel == 1) ? bk : bv;

    // folded histogram chunk (atomics fire-and-forget, overlap with staging)
    {
        int nblk = gridDim.x * gridDim.y;
        int fb = blockIdx.y * gridDim.x + blockIdx.x;
        int per = (E + nblk - 1) / nblk;
        int end = min(per * (fb + 1), E);
        for (int i = per * fb + tid; i < end; i += 256)
            atomicAdd(&deg[dst[i]], 1);
    }

    int r = tid >> 4;          // 0..15
    int c = (tid & 15) * 8;    // 0..120
    for (int rr = 0; rr < 64; rr += 16) {
        int row = rowBase + rr + r;
        int rc = (row < M) ? row : (M - 1);
        const float* p = X + (size_t)rc * 128 + c;
        float4 f0 = *(const float4*)p;
        float4 f1 = *(const float4*)(p + 4);
        short8 v;
        v[0] = (short)f2bf(f0.x); v[1] = (short)f2bf(f0.y);
        v[2] = (short)f2bf(f0.z); v[3] = (short)f2bf(f0.w);
        v[4] = (short)f2bf(f1.x); v[5] = (short)f2bf(f1.y);
        v[6] = (short)f2bf(f1.z); v[7] = (short)f2bf(f1.w);
        *(short8*)&Xs[(rr + r) * 136 + c] = v;
    }
    __syncthreads();

    int lane = tid & 63, wave = tid >> 6;
    int wm = wave * 16;
    int l15 = lane & 15, quad = lane >> 4;
    floatx4 acc[8] = {};
    for (int k0 = 0; k0 < 128; k0 += 32) {
        short8 a = *(const short8*)&Xs[(wm + l15) * 136 + k0 + quad * 8];
        for (int sn = 0; sn < 8; sn++) {
            short8 b = *(const short8*)(Wmat + (size_t)(sn * 16 + l15) * 128 + k0 + quad * 8);
            acc[sn] = __builtin_amdgcn_mfma_f32_16x16x32_bf16(a, b, acc[sn], 0, 0, 0);
        }
    }
    for (int sn = 0; sn < 8; sn++) {
        int col = sn * 16 + l15;
        float bia = bias[col];
        for (int rr2 = 0; rr2 < 4; rr2++) {
            int row = rowBase + wm + quad * 4 + rr2;
            if (row < M) {
                ushort_t val = f2bf(acc[sn][rr2] + bia);
                if (wsel == 0) {
                    Q[(size_t)row * 128 + col] = val;
                } else {
                    size_t idx = (size_t)row * 256 + ((col >> 3) << 4) + (col & 7) + ((wsel == 2) ? 8 : 0);
                    KV[idx] = val;
                }
            }
        }
    }
}

// ---------------- CSR build ----------------
__global__ __launch_bounds__(256) void k_scan_blocks(const int* __restrict__ deg, int* __restrict__ offs,
                                                     int* __restrict__ bsums, int n) {
    __shared__ int s[256];
    int i = blockIdx.x * 256 + threadIdx.x;
    int v = (i < n) ? deg[i] : 0;
    s[threadIdx.x] = v;
    __syncthreads();
    for (int d = 1; d < 256; d <<= 1) {
        int t = (threadIdx.x >= d) ? s[threadIdx.x - d] : 0;
        __syncthreads();
        s[threadIdx.x] += t;
        __syncthreads();
    }
    int incl = s[threadIdx.x];
    if (i < n) offs[i] = incl - v;  // exclusive within block
    if (threadIdx.x == 255) bsums[blockIdx.x] = incl;
}

// add_base computes its own base = sum_{b<blockIdx.x} bsums[b] (block reduce)
__global__ __launch_bounds__(256) void k_add_base(int* __restrict__ offs, int* __restrict__ cursor,
                                                  const int* __restrict__ bs, int nb, int n, int E) {
    int tid = threadIdx.x;
    int acc = 0;
    for (int t = tid; t < nb; t += 256)
        if (t < (int)blockIdx.x) acc += bs[t];
    for (int m = 1; m < 64; m <<= 1) acc += __shfl_xor(acc, m, 64);
    __shared__ int sw[4];
    if ((tid & 63) == 0) sw[tid >> 6] = acc;
    __syncthreads();
    int base = sw[0] + sw[1] + sw[2] + sw[3];
    int i = blockIdx.x * 256 + tid;
    if (i < n) {
        int o = offs[i] + base;
        offs[i] = o;
        cursor[i] = o;
    }
    if (blockIdx.x == 0 && tid == 0) offs[n] = E;
}

__global__ __launch_bounds__(256) void k_scatter(const int* __restrict__ src, const int* __restrict__ dst,
                                                 int* __restrict__ cursor, int* __restrict__ eadj, int E) {
    int i = blockIdx.x * 256 + threadIdx.x;
    if (i < E) {
        int p = atomicAdd(&cursor[dst[i]], 1);
        eadj[p] = src[i];
    }
}

// ---------------- edge attention + LN1 + LN2, one wave per dst node ----------
// Quarter-wave: group g = lane>>4 processes edge j+g; lane l15 owns dims
// 8*l15..8*l15+7 (head = l15>>1, 2 lanes/head -> 1 shfl_xor dot-reduce).
__global__ __launch_bounds__(256) void edge_attn(
    const ushort_t* __restrict__ Qb, const ushort_t* __restrict__ KV,
    const float* __restrict__ xin,
    const int* __restrict__ offs, const int* __restrict__ eadj,
    const float* __restrict__ g1, const float* __restrict__ be1,
    const float* __restrict__ g2, const float* __restrict__ be2,
    ushort_t* __restrict__ h1out, ushort_t* __restrict__ ln2out, int N)
{
    int wave = threadIdx.x >> 6, lane = threadIdx.x & 63;
    int n = blockIdx.x * 4 + wave;
    if (n >= N) return;
    int l15 = lane & 15, grp = lane >> 4;

    uint4 qp = *(const uint4*)(Qb + (size_t)n * 128 + l15 * 8);
    float q0 = u2f(qp.x << 16), q1 = u2f(qp.x & 0xffff0000u);
    float q2 = u2f(qp.y << 16), q3 = u2f(qp.y & 0xffff0000u);
    float q4 = u2f(qp.z << 16), q5 = u2f(qp.z & 0xffff0000u);
    float q6 = u2f(qp.w << 16), q7 = u2f(qp.w & 0xffff0000u);

    int s0 = offs[n], s1 = offs[n + 1];
    float a0=0.f,a1=0.f,a2=0.f,a3=0.f,a4=0.f,a5=0.f,a6=0.f,a7=0.f,z=0.f;
    for (int base = s0; base < s1; base += 64) {
        int cnt = min(s1 - base, 64);
        int ee = (base + lane < s1) ? eadj[base + lane] : 0;
        #pragma unroll 2
        for (int j = 0; j < cnt; j += 4) {
            int jj = j + grp;
            int sn = __shfl(ee, jj, 64);
            const ushort_t* kvp = KV + (size_t)sn * 256 + l15 * 16;
            uint4 kk = *(const uint4*)kvp;
            uint4 vv = *(const uint4*)(kvp + 8);
            float d0 = fmaf(q1, u2f(kk.x & 0xffff0000u), q0 * u2f(kk.x << 16));
            float d1 = fmaf(q3, u2f(kk.y & 0xffff0000u), q2 * u2f(kk.y << 16));
            float d2 = fmaf(q5, u2f(kk.z & 0xffff0000u), q4 * u2f(kk.z << 16));
            float d3 = fmaf(q7, u2f(kk.w & 0xffff0000u), q6 * u2f(kk.w << 16));
            float d = (d0 + d1) + (d2 + d3);
            d += __shfl_xor(d, 1, 64);
            float sc = fminf(5.f, fmaxf(-5.f, d * 0.25f));
            float e = (jj < cnt) ? __expf(sc) : 0.f;
            a0 = fmaf(e, u2f(vv.x << 16), a0); a1 = fmaf(e, u2f(vv.x & 0xffff0000u), a1);
            a2 = fmaf(e, u2f(vv.y << 16), a2); a3 = fmaf(e, u2f(vv.y & 0xffff0000u), a3);
            a4 = fmaf(e, u2f(vv.z << 16), a4); a5 = fmaf(e, u2f(vv.z & 0xffff0000u), a5);
            a6 = fmaf(e, u2f(vv.w << 16), a6); a7 = fmaf(e, u2f(vv.w & 0xffff0000u), a7);
            z += e;
        }
    }
    // combine across 4 groups
    a0 += __shfl_xor(a0, 16, 64); a0 += __shfl_xor(a0, 32, 64);
    a1 += __shfl_xor(a1, 16, 64); a1 += __shfl_xor(a1, 32, 64);
    a2 += __shfl_xor(a2, 16, 64); a2 += __shfl_xor(a2, 32, 64);
    a3 += __shfl_xor(a3, 16, 64); a3 += __shfl_xor(a3, 32, 64);
    a4 += __shfl_xor(a4, 16, 64); a4 += __shfl_xor(a4, 32, 64);
    a5 += __shfl_xor(a5, 16, 64); a5 += __shfl_xor(a5, 32, 64);
    a6 += __shfl_xor(a6, 16, 64); a6 += __shfl_xor(a6, 32, 64);
    a7 += __shfl_xor(a7, 16, 64); a7 += __shfl_xor(a7, 32, 64);
    z  += __shfl_xor(z, 16, 64);  z  += __shfl_xor(z, 32, 64);
    float inv = 1.f / (z + 1e-3f);

    const float* xr = xin + (size_t)n * 128 + l15 * 8;
    float4 xa = *(const float4*)xr;
    float4 xb = *(const float4*)(xr + 4);
    float t0 = xa.x + a0 * inv, t1 = xa.y + a1 * inv;
    float t2 = xa.z + a2 * inv, t3 = xa.w + a3 * inv;
    float t4 = xb.x + a4 * inv, t5 = xb.y + a5 * inv;
    float t6 = xb.z + a6 * inv, t7 = xb.w + a7 * inv;

    float s  = t0 + t1 + t2 + t3 + t4 + t5 + t6 + t7;
    float s2 = t0*t0 + t1*t1 + t2*t2 + t3*t3 + t4*t4 + t5*t5 + t6*t6 + t7*t7;
    for (int m = 1; m < 16; m <<= 1) { s += __shfl_xor(s, m, 64); s2 += __shfl_xor(s2, m, 64); }
    float mu = s * (1.f / 128.f);
    float var = s2 * (1.f / 128.f) - mu * mu;
    float rstd = rsqrtf(var + 1e-5f);

    const float* g1r = g1 + l15 * 8;
    const float* b1r = be1 + l15 * 8;
    float4 ga = *(const float4*)g1r, gb = *(const float4*)(g1r + 4);
    float4 ba = *(const float4*)b1r, bb = *(const float4*)(b1r + 4);
    float h0 = (t0 - mu) * rstd * ga.x + ba.x;
    float h1 = (t1 - mu) * rstd * ga.y + ba.y;
    float h2 = (t2 - mu) * rstd * ga.z + ba.z;
    float h3 = (t3 - mu) * rstd * ga.w + ba.w;
    float h4 = (t4 - mu) * rstd * gb.x + bb.x;
    float h5 = (t5 - mu) * rstd * gb.y + bb.y;
    float h6 = (t6 - mu) * rstd * gb.z + bb.z;
    float h7 = (t7 - mu) * rstd * gb.w + bb.w;
    if (grp == 0) {
        uint4 pk;
        pk.x = (unsigned)f2bf(h0) | ((unsigned)f2bf(h1) << 16);
        pk.y = (unsigned)f2bf(h2) | ((unsigned)f2bf(h3) << 16);
        pk.z = (unsigned)f2bf(h4) | ((unsigned)f2bf(h5) << 16);
        pk.w = (unsigned)f2bf(h6) | ((unsigned)f2bf(h7) << 16);
        *(uint4*)(h1out + (size_t)n * 128 + l15 * 8) = pk;
    }

    s  = h0 + h1 + h2 + h3 + h4 + h5 + h6 + h7;
    s2 = h0*h0 + h1*h1 + h2*h2 + h3*h3 + h4*h4 + h5*h5 + h6*h6 + h7*h7;
    for (int m = 1; m < 16; m <<= 1) { s += __shfl_xor(s, m, 64); s2 += __shfl_xor(s2, m, 64); }
    float mu2 = s * (1.f / 128.f);
    float var2 = s2 * (1.f / 128.f) - mu2 * mu2;
    float rstd2 = rsqrtf(var2 + 1e-5f);

    const float* g2r = g2 + l15 * 8;
    const float* b2r = be2 + l15 * 8;
    float4 gc = *(const float4*)g2r, gd = *(const float4*)(g2r + 4);
    float4 bc = *(const float4*)b2r, bd = *(const float4*)(b2r + 4);
    float l0 = (h0 - mu2) * rstd2 * gc.x + bc.x;
    float l1 = (h1 - mu2) * rstd2 * gc.y + bc.y;
    float l2 = (h2 - mu2) * rstd2 * gc.z + bc.z;
    float l3 = (h3 - mu2) * rstd2 * gc.w + bc.w;
    float l4 = (h4 - mu2) * rstd2 * gd.x + bd.x;
    float l5 = (h5 - mu2) * rstd2 * gd.y + bd.y;
    float l6 = (h6 - mu2) * rstd2 * gd.z + bd.z;
    float l7 = (h7 - mu2) * rstd2 * gd.w + bd.w;
    if (grp == 1) {
        uint4 pk;
        pk.x = (unsigned)f2bf(l0) | ((unsigned)f2bf(l1) << 16);
        pk.y = (unsigned)f2bf(l2) | ((unsigned)f2bf(l3) << 16);
        pk.z = (unsigned)f2bf(l4) | ((unsigned)f2bf(l5) << 16);
        pk.w = (unsigned)f2bf(l6) | ((unsigned)f2bf(l7) << 16);
        *(uint4*)(ln2out + (size_t)n * 128 + l15 * 8) = pk;
    }
}

// -------- output GEMM: A in LDS, B register-direct; out = h1 + relu(...) -----
// grid (rows, 2): colBase = blockIdx.y*64; wave = 16 rows x 64 cols.
__global__ __launch_bounds__(256) void gemm_o(
    const ushort_t* __restrict__ X, const ushort_t* __restrict__ Wt,
    const float* __restrict__ bo, const ushort_t* __restrict__ h1in,
    float* __restrict__ Out, int M)
{
    __shared__ ushort_t As[64 * 136];
    int tid = threadIdx.x;
    int rowBase = blockIdx.x * 64;
    int colBase = blockIdx.y * 64;

    int r = tid >> 4;
    int c = (tid & 15) * 8;
    for (int rr = 0; rr < 64; rr += 16) {
        int row = rowBase + rr + r;
        int rc = (row < M) ? row : (M - 1);
        short8 v = *(const short8*)(X + (size_t)rc * 128 + c);
        *(short8*)&As[(rr + r) * 136 + c] = v;
    }
    __syncthreads();

    int lane = tid & 63, wave = tid >> 6;
    int wm = wave * 16;
    int l15 = lane & 15, quad = lane >> 4;
    floatx4 acc[4] = {};
    for (int k0 = 0; k0 < 128; k0 += 32) {
        short8 a = *(const short8*)&As[(wm + l15) * 136 + k0 + quad * 8];
        for (int sn = 0; sn < 4; sn++) {
            int col = colBase + sn * 16 + l15;
            short8 b = *(const short8*)(Wt + (size_t)col * 128 + k0 + quad * 8);
            acc[sn] = __builtin_amdgcn_mfma_f32_16x16x32_bf16(a, b, acc[sn], 0, 0, 0);
        }
    }
    for (int sn = 0; sn < 4; sn++) {
        int col = colBase + sn * 16 + l15;
        float bia = bo[col];
        for (int rr2 = 0; rr2 < 4; rr2++) {
            int row = rowBase + wm + quad * 4 + rr2;
            if (row < M) {
                float v = fmaxf(acc[sn][rr2] + bia, 0.f);
                float hv = bf2f(h1in[(size_t)row * 128 + col]);
                Out[(size_t)row * 128 + col] = hv + v;
            }
        }
    }
}

extern "C" void kernel_launch(void* const* d_in, const int* in_sizes, int n_in,
                              void* d_out, int out_size, void* d_ws, size_t ws_size,
                              hipStream_t stream) {
    const int D = 128;
    const int N = in_sizes[0] / D;
    const int E = in_sizes[1];

    const float* x   = (const float*)d_in[0];
    const int*   src = (const int*)d_in[1];
    const int*   dst = (const int*)d_in[2];
    const float* Wq  = (const float*)d_in[3];
    const float* bq  = (const float*)d_in[4];
    const float* Wk  = (const float*)d_in[5];
    const float* bk  = (const float*)d_in[6];
    const float* Wv  = (const float*)d_in[7];
    const float* bv  = (const float*)d_in[8];
    const float* Wo  = (const float*)d_in[9];
    const float* bo  = (const float*)d_in[10];
    const float* g1  = (const float*)d_in[11];
    const float* be1 = (const float*)d_in[12];
    const float* g2  = (const float*)d_in[13];
    const float* be2 = (const float*)d_in[14];

    char* ws = (char*)d_ws;
    size_t o = 0;
    auto alloc = [&](size_t b) { o = (o + 255) & ~(size_t)255; size_t r = o; o += b; return r; };
    ushort_t* Qb   = (ushort_t*)(ws + alloc((size_t)N * D * 2));
    ushort_t* KVb  = (ushort_t*)(ws + alloc((size_t)N * D * 4));   // interleaved K,V (8-granular)
    ushort_t* ln2  = (ushort_t*)(ws + alloc((size_t)N * D * 2));
    ushort_t* h1   = (ushort_t*)(ws + alloc((size_t)N * D * 2));   // bf16
    ushort_t* Wt   = (ushort_t*)(ws + alloc((size_t)4 * 128 * 128 * 2));
    int*      deg  = (int*)(ws + alloc((size_t)N * 4));
    int*      offs = (int*)(ws + alloc((size_t)(N + 1) * 4));
    int*      cur  = (int*)(ws + alloc((size_t)N * 4));
    int*      bsum = (int*)(ws + alloc((size_t)256 * 4));
    int*      eadj = (int*)(ws + alloc((size_t)E * 4));

    int nScanBlocks = (N + 255) / 256;
    int nEdgeBlocks = (E + 255) / 256;
    int nRowTiles = (N + 63) / 64;

    hipMemsetAsync(deg, 0, (size_t)N * 4, stream);
    transpose128<<<dim3(16, 4), 256, 0, stream>>>(Wq, Wk, Wv, Wo, Wt);
    gemm_qkv<<<dim3(nRowTiles, 3), 256, 0, stream>>>(x, Wt, bq, bk, bv, Qb, KVb, N, dst, deg, E);
    k_scan_blocks<<<nScanBlocks, 256, 0, stream>>>(deg, offs, bsum, N);
    k_add_base<<<nScanBlocks, 256, 0, stream>>>(offs, cur, bsum, nScanBlocks, N, E);
    k_scatter<<<nEdgeBlocks, 256, 0, stream>>>(src, dst, cur, eadj, E);
    edge_attn<<<(N + 3) / 4, 256, 0, stream>>>(Qb, KVb, x, offs, eadj, g1, be1, g2, be2, h1, ln2, N);
    gemm_o<<<dim3(nRowTiles, 2), 256, 0, stream>>>(ln2, Wt + 3 * 128 * 128, bo, h1, (float*)d_out, N);
}

// Round 9
// 285.654 us; speedup vs baseline: 1.0977x; 1.0977x over previous
//
#include <hip/hip_runtime.h>
#include <hip/hip_bf16.h>

typedef unsigned short ushort_t;
typedef __attribute__((ext_vector_type(8))) short short8;
typedef __attribute__((ext_vector_type(4))) float floatx4;

__device__ __forceinline__ unsigned short f2bf(float f) {
    union { float f; unsigned u; } x; x.f = f;
    unsigned r = x.u + 0x7fffu + ((x.u >> 16) & 1u);  // RNE
    return (unsigned short)(r >> 16);
}
__device__ __forceinline__ float bf2f(unsigned short u) {
    union { unsigned u; float f; } x; x.u = ((unsigned)u) << 16; return x.f;
}
__device__ __forceinline__ float u2f(unsigned u) {
    union { unsigned u; float f; } x; x.u = u; return x.f;
}

// ------ transpose+convert weights -> bf16 in MFMA B-fragment order -----------
// For W (128x128, row-major [k][n]), B^T fragment for tile (sn,kb):
// lane (quad*16+l15) holds B^T[n=sn*16+l15][k=kb*32+quad*8+j], j=0..7.
// Stored at Wsw[(sn*4+kb)*512 + lane*8 + j] -> B-load is coalesced 16B/lane.
__global__ __launch_bounds__(256) void transpose_swz(
    const float* __restrict__ Wq, const float* __restrict__ Wk,
    const float* __restrict__ Wv, const float* __restrict__ Wo,
    ushort_t* __restrict__ out)
{
    const float* W = (blockIdx.y == 0) ? Wq : (blockIdx.y == 1) ? Wk :
                     (blockIdx.y == 2) ? Wv : Wo;
    ushort_t* T = out + (size_t)blockIdx.y * 128 * 128;
    int t = blockIdx.x * 256 + threadIdx.x;   // 0..2047
    int kg = t >> 7;        // 0..15  (k-group of 8)
    int n  = t & 127;
    int k0 = kg * 8;
    short8 v;
    #pragma unroll
    for (int j = 0; j < 8; j++)
        v[j] = (short)f2bf(W[(size_t)(k0 + j) * 128 + n]);
    int sn = n >> 4, l15 = n & 15, kb = kg >> 2, quad = kg & 3;
    size_t f = ((size_t)((sn * 4 + kb) * 4 + quad)) * 128 + (size_t)l15 * 8;
    *(short8*)(T + f) = v;
}

// ------------- QKV GEMM: A in LDS, B register-direct (swizzled, L1) ----------
// grid (rows,3). Q -> [M,128] bf16. KV 8-interleaved: row n, col c:
// K at n*256+(c>>3)*16+(c&7), V at +8.  Folded dst-histogram per block.
__global__ __launch_bounds__(256) void gemm_qkv(
    const float* __restrict__ X, const ushort_t* __restrict__ Wsw,
    const float* __restrict__ bq, const float* __restrict__ bk, const float* __restrict__ bv,
    ushort_t* __restrict__ Q, ushort_t* __restrict__ KV, int M,
    const int* __restrict__ dst, int* __restrict__ deg, int E)
{
    __shared__ ushort_t Xs[64 * 136];
    int tid = threadIdx.x;
    int rowBase = blockIdx.x * 64;
    int wsel = blockIdx.y;
    const ushort_t* Wmat = Wsw + (size_t)wsel * 128 * 128;  // fragment-order
    const float* bias = (wsel == 0) ? bq : (wsel == 1) ? bk : bv;

    // folded histogram chunk
    {
        int nblk = gridDim.x * gridDim.y;
        int fb = blockIdx.y * gridDim.x + blockIdx.x;
        int per = (E + nblk - 1) / nblk;
        int end = min(per * (fb + 1), E);
        for (int i = per * fb + tid; i < end; i += 256)
            atomicAdd(&deg[dst[i]], 1);
    }

    int r = tid >> 4;          // 0..15
    int c = (tid & 15) * 8;    // 0..120
    for (int rr = 0; rr < 64; rr += 16) {
        int row = rowBase + rr + r;
        int rc = (row < M) ? row : (M - 1);
        const float* p = X + (size_t)rc * 128 + c;
        float4 f0 = *(const float4*)p;
        float4 f1 = *(const float4*)(p + 4);
        short8 v;
        v[0] = (short)f2bf(f0.x); v[1] = (short)f2bf(f0.y);
        v[2] = (short)f2bf(f0.z); v[3] = (short)f2bf(f0.w);
        v[4] = (short)f2bf(f1.x); v[5] = (short)f2bf(f1.y);
        v[6] = (short)f2bf(f1.z); v[7] = (short)f2bf(f1.w);
        *(short8*)&Xs[(rr + r) * 136 + c] = v;
    }
    __syncthreads();

    int lane = tid & 63, wave = tid >> 6;
    int wm = wave * 16;
    int l15 = lane & 15, quad = lane >> 4;
    floatx4 acc[8] = {};
    for (int kb = 0; kb < 4; kb++) {
        short8 a = *(const short8*)&Xs[(wm + l15) * 136 + kb * 32 + quad * 8];
        for (int sn = 0; sn < 8; sn++) {
            short8 b = *(const short8*)(Wmat + (size_t)(sn * 4 + kb) * 512 + lane * 8);
            acc[sn] = __builtin_amdgcn_mfma_f32_16x16x32_bf16(a, b, acc[sn], 0, 0, 0);
        }
    }
    for (int sn = 0; sn < 8; sn++) {
        int col = sn * 16 + l15;
        float bia = bias[col];
        for (int rr2 = 0; rr2 < 4; rr2++) {
            int row = rowBase + wm + quad * 4 + rr2;
            if (row < M) {
                ushort_t val = f2bf(acc[sn][rr2] + bia);
                if (wsel == 0) {
                    Q[(size_t)row * 128 + col] = val;
                } else {
                    size_t idx = (size_t)row * 256 + ((col >> 3) << 4) + (col & 7) + ((wsel == 2) ? 8 : 0);
                    KV[idx] = val;
                }
            }
        }
    }
}

// ---------------- CSR build ----------------
__global__ __launch_bounds__(256) void k_scan_blocks(const int* __restrict__ deg, int* __restrict__ offs,
                                                     int* __restrict__ bsums, int n) {
    __shared__ int s[256];
    int i = blockIdx.x * 256 + threadIdx.x;
    int v = (i < n) ? deg[i] : 0;
    s[threadIdx.x] = v;
    __syncthreads();
    for (int d = 1; d < 256; d <<= 1) {
        int t = (threadIdx.x >= d) ? s[threadIdx.x - d] : 0;
        __syncthreads();
        s[threadIdx.x] += t;
        __syncthreads();
    }
    int incl = s[threadIdx.x];
    if (i < n) offs[i] = incl - v;  // exclusive within block
    if (threadIdx.x == 255) bsums[blockIdx.x] = incl;
}

// add_base computes its own base = sum_{b<blockIdx.x} bsums[b] (block reduce)
__global__ __launch_bounds__(256) void k_add_base(int* __restrict__ offs, int* __restrict__ cursor,
                                                  const int* __restrict__ bs, int nb, int n, int E) {
    int tid = threadIdx.x;
    int acc = 0;
    for (int t = tid; t < nb; t += 256)
        if (t < (int)blockIdx.x) acc += bs[t];
    for (int m = 1; m < 64; m <<= 1) acc += __shfl_xor(acc, m, 64);
    __shared__ int sw[4];
    if ((tid & 63) == 0) sw[tid >> 6] = acc;
    __syncthreads();
    int base = sw[0] + sw[1] + sw[2] + sw[3];
    int i = blockIdx.x * 256 + tid;
    if (i < n) {
        int o = offs[i] + base;
        offs[i] = o;
        cursor[i] = o;
    }
    if (blockIdx.x == 0 && tid == 0) offs[n] = E;
}

__global__ __launch_bounds__(256) void k_scatter(const int* __restrict__ src, const int* __restrict__ dst,
                                                 int* __restrict__ cursor, int* __restrict__ eadj, int E) {
    int i = blockIdx.x * 256 + threadIdx.x;
    if (i < E) {
        int p = atomicAdd(&cursor[dst[i]], 1);
        eadj[p] = src[i];
    }
}

// ---------------- edge attention + LN1 + LN2, one wave per dst node ----------
// Quarter-wave: group g = lane>>4 processes edge j+g; lane l15 owns dims
// 8*l15..8*l15+7 (head = l15>>1, 2 lanes/head -> 1 shfl_xor dot-reduce).
__global__ __launch_bounds__(256) void edge_attn(
    const ushort_t* __restrict__ Qb, const ushort_t* __restrict__ KV,
    const float* __restrict__ xin,
    const int* __restrict__ offs, const int* __restrict__ eadj,
    const float* __restrict__ g1, const float* __restrict__ be1,
    const float* __restrict__ g2, const float* __restrict__ be2,
    ushort_t* __restrict__ h1out, ushort_t* __restrict__ ln2out, int N)
{
    int wave = threadIdx.x >> 6, lane = threadIdx.x & 63;
    int n = blockIdx.x * 4 + wave;
    if (n >= N) return;
    int l15 = lane & 15, grp = lane >> 4;

    uint4 qp = *(const uint4*)(Qb + (size_t)n * 128 + l15 * 8);
    float q0 = u2f(qp.x << 16), q1 = u2f(qp.x & 0xffff0000u);
    float q2 = u2f(qp.y << 16), q3 = u2f(qp.y & 0xffff0000u);
    float q4 = u2f(qp.z << 16), q5 = u2f(qp.z & 0xffff0000u);
    float q6 = u2f(qp.w << 16), q7 = u2f(qp.w & 0xffff0000u);

    int s0 = offs[n], s1 = offs[n + 1];
    float a0=0.f,a1=0.f,a2=0.f,a3=0.f,a4=0.f,a5=0.f,a6=0.f,a7=0.f,z=0.f;
    for (int base = s0; base < s1; base += 64) {
        int cnt = min(s1 - base, 64);
        int ee = (base + lane < s1) ? eadj[base + lane] : 0;
        #pragma unroll 2
        for (int j = 0; j < cnt; j += 4) {
            int jj = j + grp;
            int sn = __shfl(ee, jj, 64);
            const ushort_t* kvp = KV + (size_t)sn * 256 + l15 * 16;
            uint4 kk = *(const uint4*)kvp;
            uint4 vv = *(const uint4*)(kvp + 8);
            float d0 = fmaf(q1, u2f(kk.x & 0xffff0000u), q0 * u2f(kk.x << 16));
            float d1 = fmaf(q3, u2f(kk.y & 0xffff0000u), q2 * u2f(kk.y << 16));
            float d2 = fmaf(q5, u2f(kk.z & 0xffff0000u), q4 * u2f(kk.z << 16));
            float d3 = fmaf(q7, u2f(kk.w & 0xffff0000u), q6 * u2f(kk.w << 16));
            float d = (d0 + d1) + (d2 + d3);
            d += __shfl_xor(d, 1, 64);
            float sc = fminf(5.f, fmaxf(-5.f, d * 0.25f));
            float e = (jj < cnt) ? __expf(sc) : 0.f;
            a0 = fmaf(e, u2f(vv.x << 16), a0); a1 = fmaf(e, u2f(vv.x & 0xffff0000u), a1);
            a2 = fmaf(e, u2f(vv.y << 16), a2); a3 = fmaf(e, u2f(vv.y & 0xffff0000u), a3);
            a4 = fmaf(e, u2f(vv.z << 16), a4); a5 = fmaf(e, u2f(vv.z & 0xffff0000u), a5);
            a6 = fmaf(e, u2f(vv.w << 16), a6); a7 = fmaf(e, u2f(vv.w & 0xffff0000u), a7);
            z += e;
        }
    }
    // combine across 4 groups
    a0 += __shfl_xor(a0, 16, 64); a0 += __shfl_xor(a0, 32, 64);
    a1 += __shfl_xor(a1, 16, 64); a1 += __shfl_xor(a1, 32, 64);
    a2 += __shfl_xor(a2, 16, 64); a2 += __shfl_xor(a2, 32, 64);
    a3 += __shfl_xor(a3, 16, 64); a3 += __shfl_xor(a3, 32, 64);
    a4 += __shfl_xor(a4, 16, 64); a4 += __shfl_xor(a4, 32, 64);
    a5 += __shfl_xor(a5, 16, 64); a5 += __shfl_xor(a5, 32, 64);
    a6 += __shfl_xor(a6, 16, 64); a6 += __shfl_xor(a6, 32, 64);
    a7 += __shfl_xor(a7, 16, 64); a7 += __shfl_xor(a7, 32, 64);
    z  += __shfl_xor(z, 16, 64);  z  += __shfl_xor(z, 32, 64);
    float inv = 1.f / (z + 1e-3f);

    const float* xr = xin + (size_t)n * 128 + l15 * 8;
    float4 xa = *(const float4*)xr;
    float4 xb = *(const float4*)(xr + 4);
    float t0 = xa.x + a0 * inv, t1 = xa.y + a1 * inv;
    float t2 = xa.z + a2 * inv, t3 = xa.w + a3 * inv;
    float t4 = xb.x + a4 * inv, t5 = xb.y + a5 * inv;
    float t6 = xb.z + a6 * inv, t7 = xb.w + a7 * inv;

    float s  = t0 + t1 + t2 + t3 + t4 + t5 + t6 + t7;
    float s2 = t0*t0 + t1*t1 + t2*t2 + t3*t3 + t4*t4 + t5*t5 + t6*t6 + t7*t7;
    for (int m = 1; m < 16; m <<= 1) { s += __shfl_xor(s, m, 64); s2 += __shfl_xor(s2, m, 64); }
    float mu = s * (1.f / 128.f);
    float var = s2 * (1.f / 128.f) - mu * mu;
    float rstd = rsqrtf(var + 1e-5f);

    const float* g1r = g1 + l15 * 8;
    const float* b1r = be1 + l15 * 8;
    float4 ga = *(const float4*)g1r, gb = *(const float4*)(g1r + 4);
    float4 ba = *(const float4*)b1r, bb = *(const float4*)(b1r + 4);
    float h0 = (t0 - mu) * rstd * ga.x + ba.x;
    float h1 = (t1 - mu) * rstd * ga.y + ba.y;
    float h2 = (t2 - mu) * rstd * ga.z + ba.z;
    float h3 = (t3 - mu) * rstd * ga.w + ba.w;
    float h4 = (t4 - mu) * rstd * gb.x + bb.x;
    float h5 = (t5 - mu) * rstd * gb.y + bb.y;
    float h6 = (t6 - mu) * rstd * gb.z + bb.z;
    float h7 = (t7 - mu) * rstd * gb.w + bb.w;
    if (grp == 0) {
        uint4 pk;
        pk.x = (unsigned)f2bf(h0) | ((unsigned)f2bf(h1) << 16);
        pk.y = (unsigned)f2bf(h2) | ((unsigned)f2bf(h3) << 16);
        pk.z = (unsigned)f2bf(h4) | ((unsigned)f2bf(h5) << 16);
        pk.w = (unsigned)f2bf(h6) | ((unsigned)f2bf(h7) << 16);
        *(uint4*)(h1out + (size_t)n * 128 + l15 * 8) = pk;
    }

    s  = h0 + h1 + h2 + h3 + h4 + h5 + h6 + h7;
    s2 = h0*h0 + h1*h1 + h2*h2 + h3*h3 + h4*h4 + h5*h5 + h6*h6 + h7*h7;
    for (int m = 1; m < 16; m <<= 1) { s += __shfl_xor(s, m, 64); s2 += __shfl_xor(s2, m, 64); }
    float mu2 = s * (1.f / 128.f);
    float var2 = s2 * (1.f / 128.f) - mu2 * mu2;
    float rstd2 = rsqrtf(var2 + 1e-5f);

    const float* g2r = g2 + l15 * 8;
    const float* b2r = be2 + l15 * 8;
    float4 gc = *(const float4*)g2r, gd = *(const float4*)(g2r + 4);
    float4 bc = *(const float4*)b2r, bd = *(const float4*)(b2r + 4);
    float l0 = (h0 - mu2) * rstd2 * gc.x + bc.x;
    float l1 = (h1 - mu2) * rstd2 * gc.y + bc.y;
    float l2 = (h2 - mu2) * rstd2 * gc.z + bc.z;
    float l3 = (h3 - mu2) * rstd2 * gc.w + bc.w;
    float l4 = (h4 - mu2) * rstd2 * gd.x + bd.x;
    float l5 = (h5 - mu2) * rstd2 * gd.y + bd.y;
    float l6 = (h6 - mu2) * rstd2 * gd.z + bd.z;
    float l7 = (h7 - mu2) * rstd2 * gd.w + bd.w;
    if (grp == 1) {
        uint4 pk;
        pk.x = (unsigned)f2bf(l0) | ((unsigned)f2bf(l1) << 16);
        pk.y = (unsigned)f2bf(l2) | ((unsigned)f2bf(l3) << 16);
        pk.z = (unsigned)f2bf(l4) | ((unsigned)f2bf(l5) << 16);
        pk.w = (unsigned)f2bf(l6) | ((unsigned)f2bf(l7) << 16);
        *(uint4*)(ln2out + (size_t)n * 128 + l15 * 8) = pk;
    }
}

// ------ output GEMM: A in LDS, B register-direct (swizzled, L1) --------------
// grid (rows, 2): colBase = blockIdx.y*64; snBase = blockIdx.y*4.
__global__ __launch_bounds__(256) void gemm_o(
    const ushort_t* __restrict__ X, const ushort_t* __restrict__ Wsw,
    const float* __restrict__ bo, const ushort_t* __restrict__ h1in,
    float* __restrict__ Out, int M)
{
    __shared__ ushort_t As[64 * 136];
    int tid = threadIdx.x;
    int rowBase = blockIdx.x * 64;
    int snBase = blockIdx.y * 4;

    int r = tid >> 4;
    int c = (tid & 15) * 8;
    for (int rr = 0; rr < 64; rr += 16) {
        int row = rowBase + rr + r;
        int rc = (row < M) ? row : (M - 1);
        short8 v = *(const short8*)(X + (size_t)rc * 128 + c);
        *(short8*)&As[(rr + r) * 136 + c] = v;
    }
    __syncthreads();

    int lane = tid & 63, wave = tid >> 6;
    int wm = wave * 16;
    int l15 = lane & 15, quad = lane >> 4;
    floatx4 acc[4] = {};
    for (int kb = 0; kb < 4; kb++) {
        short8 a = *(const short8*)&As[(wm + l15) * 136 + kb * 32 + quad * 8];
        for (int s = 0; s < 4; s++) {
            short8 b = *(const short8*)(Wsw + (size_t)((snBase + s) * 4 + kb) * 512 + lane * 8);
            acc[s] = __builtin_amdgcn_mfma_f32_16x16x32_bf16(a, b, acc[s], 0, 0, 0);
        }
    }
    for (int s = 0; s < 4; s++) {
        int col = (snBase + s) * 16 + l15;
        float bia = bo[col];
        for (int rr2 = 0; rr2 < 4; rr2++) {
            int row = rowBase + wm + quad * 4 + rr2;
            if (row < M) {
                float v = fmaxf(acc[s][rr2] + bia, 0.f);
                float hv = bf2f(h1in[(size_t)row * 128 + col]);
                Out[(size_t)row * 128 + col] = hv + v;
            }
        }
    }
}

extern "C" void kernel_launch(void* const* d_in, const int* in_sizes, int n_in,
                              void* d_out, int out_size, void* d_ws, size_t ws_size,
                              hipStream_t stream) {
    const int D = 128;
    const int N = in_sizes[0] / D;
    const int E = in_sizes[1];

    const float* x   = (const float*)d_in[0];
    const int*   src = (const int*)d_in[1];
    const int*   dst = (const int*)d_in[2];
    const float* Wq  = (const float*)d_in[3];
    const float* bq  = (const float*)d_in[4];
    const float* Wk  = (const float*)d_in[5];
    const float* bk  = (const float*)d_in[6];
    const float* Wv  = (const float*)d_in[7];
    const float* bv  = (const float*)d_in[8];
    const float* Wo  = (const float*)d_in[9];
    const float* bo  = (const float*)d_in[10];
    const float* g1  = (const float*)d_in[11];
    const float* be1 = (const float*)d_in[12];
    const float* g2  = (const float*)d_in[13];
    const float* be2 = (const float*)d_in[14];

    char* ws = (char*)d_ws;
    size_t o = 0;
    auto alloc = [&](size_t b) { o = (o + 255) & ~(size_t)255; size_t r = o; o += b; return r; };
    ushort_t* Qb   = (ushort_t*)(ws + alloc((size_t)N * D * 2));
    ushort_t* KVb  = (ushort_t*)(ws + alloc((size_t)N * D * 4));   // interleaved K,V (8-granular)
    ushort_t* ln2  = (ushort_t*)(ws + alloc((size_t)N * D * 2));
    ushort_t* h1   = (ushort_t*)(ws + alloc((size_t)N * D * 2));   // bf16
    ushort_t* Wt   = (ushort_t*)(ws + alloc((size_t)4 * 128 * 128 * 2));  // swizzled
    int*      deg  = (int*)(ws + alloc((size_t)N * 4));
    int*      offs = (int*)(ws + alloc((size_t)(N + 1) * 4));
    int*      cur  = (int*)(ws + alloc((size_t)N * 4));
    int*      bsum = (int*)(ws + alloc((size_t)256 * 4));
    int*      eadj = (int*)(ws + alloc((size_t)E * 4));

    int nScanBlocks = (N + 255) / 256;
    int nEdgeBlocks = (E + 255) / 256;
    int nRowTiles = (N + 63) / 64;

    hipMemsetAsync(deg, 0, (size_t)N * 4, stream);
    transpose_swz<<<dim3(8, 4), 256, 0, stream>>>(Wq, Wk, Wv, Wo, Wt);
    gemm_qkv<<<dim3(nRowTiles, 3), 256, 0, stream>>>(x, Wt, bq, bk, bv, Qb, KVb, N, dst, deg, E);
    k_scan_blocks<<<nScanBlocks, 256, 0, stream>>>(deg, offs, bsum, N);
    k_add_base<<<nScanBlocks, 256, 0, stream>>>(offs, cur, bsum, nScanBlocks, N, E);
    k_scatter<<<nEdgeBlocks, 256, 0, stream>>>(src, dst, cur, eadj, E);
    edge_attn<<<(N + 3) / 4, 256, 0, stream>>>(Qb, KVb, x, offs, eadj, g1, be1, g2, be2, h1, ln2, N);
    gemm_o<<<dim3(nRowTiles, 2), 256, 0, stream>>>(ln2, Wt + 3 * 128 * 128, bo, h1, (float*)d_out, N);
}

// Round 10
// 272.090 us; speedup vs baseline: 1.1524x; 1.0499x over previous
//
#include <hip/hip_runtime.h>
#include <hip/hip_bf16.h>

typedef unsigned short ushort_t;
typedef __attribute__((ext_vector_type(8))) short short8;
typedef __attribute__((ext_vector_type(4))) float floatx4;

__device__ __forceinline__ unsigned short f2bf(float f) {
    union { float f; unsigned u; } x; x.f = f;
    unsigned r = x.u + 0x7fffu + ((x.u >> 16) & 1u);  // RNE
    return (unsigned short)(r >> 16);
}
__device__ __forceinline__ float bf2f(unsigned short u) {
    union { unsigned u; float f; } x; x.u = ((unsigned)u) << 16; return x.f;
}
__device__ __forceinline__ float u2f(unsigned u) {
    union { unsigned u; float f; } x; x.u = u; return x.f;
}

// ------ transpose+convert weights -> bf16 in MFMA B-fragment order -----------
__global__ __launch_bounds__(256) void transpose_swz(
    const float* __restrict__ Wq, const float* __restrict__ Wk,
    const float* __restrict__ Wv, const float* __restrict__ Wo,
    ushort_t* __restrict__ out)
{
    const float* W = (blockIdx.y == 0) ? Wq : (blockIdx.y == 1) ? Wk :
                     (blockIdx.y == 2) ? Wv : Wo;
    ushort_t* T = out + (size_t)blockIdx.y * 128 * 128;
    int t = blockIdx.x * 256 + threadIdx.x;   // 0..2047
    int kg = t >> 7;        // 0..15  (k-group of 8)
    int n  = t & 127;
    int k0 = kg * 8;
    short8 v;
    #pragma unroll
    for (int j = 0; j < 8; j++)
        v[j] = (short)f2bf(W[(size_t)(k0 + j) * 128 + n]);
    int sn = n >> 4, l15 = n & 15, kb = kg >> 2, quad = kg & 3;
    size_t f = ((size_t)((sn * 4 + kb) * 4 + quad)) * 128 + (size_t)l15 * 8;
    *(short8*)(T + f) = v;
}

// ------------- QKV GEMM: A in LDS, B swizzled-direct, coalesced epilogue -----
// grid (rows,3). Q -> [M,128] bf16. KV 8-interleaved: row n, col c:
// K at n*256+(c>>3)*16+(c&7), V at +8.  Folded dst-histogram per block.
__global__ __launch_bounds__(256) void gemm_qkv(
    const float* __restrict__ X, const ushort_t* __restrict__ Wsw,
    const float* __restrict__ bq, const float* __restrict__ bk, const float* __restrict__ bv,
    ushort_t* __restrict__ Q, ushort_t* __restrict__ KV, int M,
    const int* __restrict__ dst, int* __restrict__ deg, int E)
{
    __shared__ ushort_t Xs[64 * 136];
    int tid = threadIdx.x;
    int rowBase = blockIdx.x * 64;
    int wsel = blockIdx.y;
    const ushort_t* Wmat = Wsw + (size_t)wsel * 128 * 128;  // fragment-order
    const float* bias = (wsel == 0) ? bq : (wsel == 1) ? bk : bv;

    // folded histogram chunk
    {
        int nblk = gridDim.x * gridDim.y;
        int fb = blockIdx.y * gridDim.x + blockIdx.x;
        int per = (E + nblk - 1) / nblk;
        int end = min(per * (fb + 1), E);
        for (int i = per * fb + tid; i < end; i += 256)
            atomicAdd(&deg[dst[i]], 1);
    }

    int r = tid >> 4;          // 0..15
    int c = (tid & 15) * 8;    // 0..120
    for (int rr = 0; rr < 64; rr += 16) {
        int row = rowBase + rr + r;
        int rc = (row < M) ? row : (M - 1);
        const float* p = X + (size_t)rc * 128 + c;
        float4 f0 = *(const float4*)p;
        float4 f1 = *(const float4*)(p + 4);
        short8 v;
        v[0] = (short)f2bf(f0.x); v[1] = (short)f2bf(f0.y);
        v[2] = (short)f2bf(f0.z); v[3] = (short)f2bf(f0.w);
        v[4] = (short)f2bf(f1.x); v[5] = (short)f2bf(f1.y);
        v[6] = (short)f2bf(f1.z); v[7] = (short)f2bf(f1.w);
        *(short8*)&Xs[(rr + r) * 136 + c] = v;
    }
    __syncthreads();

    int lane = tid & 63, wave = tid >> 6;
    int wm = wave * 16;
    int l15 = lane & 15, quad = lane >> 4;
    floatx4 acc[8] = {};
    for (int kb = 0; kb < 4; kb++) {
        short8 a = *(const short8*)&Xs[(wm + l15) * 136 + kb * 32 + quad * 8];
        for (int sn = 0; sn < 8; sn++) {
            short8 b = *(const short8*)(Wmat + (size_t)(sn * 4 + kb) * 512 + lane * 8);
            acc[sn] = __builtin_amdgcn_mfma_f32_16x16x32_bf16(a, b, acc[sn], 0, 0, 0);
        }
    }

    // stage C (bf16) into Xs rows [wm..wm+15] (wave-private; DS in-order)
    for (int sn = 0; sn < 8; sn++) {
        int col = sn * 16 + l15;
        float bia = bias[col];
        for (int rr2 = 0; rr2 < 4; rr2++) {
            int rl = wm + quad * 4 + rr2;
            Xs[rl * 136 + col] = f2bf(acc[sn][rr2] + bia);
        }
    }
    // coalesced write-out: 4 iters x 64 lanes x 16B
    for (int it = 0; it < 4; it++) {
        int idx = it * 64 + lane;
        int rl = idx >> 4;               // 0..15
        int seg = idx & 15;              // 16B segment (cols 8*seg..8*seg+7)
        int row = rowBase + wm + rl;
        if (row < M) {
            short8 v = *(const short8*)&Xs[(wm + rl) * 136 + seg * 8];
            if (wsel == 0) {
                *(short8*)(Q + (size_t)row * 128 + seg * 8) = v;
            } else {
                *(short8*)(KV + (size_t)row * 256 + seg * 16 + ((wsel == 2) ? 8 : 0)) = v;
            }
        }
    }
}

// ---------------- CSR build ----------------
__global__ __launch_bounds__(256) void k_scan_blocks(const int* __restrict__ deg, int* __restrict__ offs,
                                                     int* __restrict__ bsums, int n) {
    __shared__ int s[256];
    int i = blockIdx.x * 256 + threadIdx.x;
    int v = (i < n) ? deg[i] : 0;
    s[threadIdx.x] = v;
    __syncthreads();
    for (int d = 1; d < 256; d <<= 1) {
        int t = (threadIdx.x >= d) ? s[threadIdx.x - d] : 0;
        __syncthreads();
        s[threadIdx.x] += t;
        __syncthreads();
    }
    int incl = s[threadIdx.x];
    if (i < n) offs[i] = incl - v;  // exclusive within block
    if (threadIdx.x == 255) bsums[blockIdx.x] = incl;
}

__global__ __launch_bounds__(256) void k_add_base(int* __restrict__ offs, int* __restrict__ cursor,
                                                  const int* __restrict__ bs, int nb, int n, int E) {
    int tid = threadIdx.x;
    int acc = 0;
    for (int t = tid; t < nb; t += 256)
        if (t < (int)blockIdx.x) acc += bs[t];
    for (int m = 1; m < 64; m <<= 1) acc += __shfl_xor(acc, m, 64);
    __shared__ int sw[4];
    if ((tid & 63) == 0) sw[tid >> 6] = acc;
    __syncthreads();
    int base = sw[0] + sw[1] + sw[2] + sw[3];
    int i = blockIdx.x * 256 + tid;
    if (i < n) {
        int o = offs[i] + base;
        offs[i] = o;
        cursor[i] = o;
    }
    if (blockIdx.x == 0 && tid == 0) offs[n] = E;
}

__global__ __launch_bounds__(256) void k_scatter(const int* __restrict__ src, const int* __restrict__ dst,
                                                 int* __restrict__ cursor, int* __restrict__ eadj, int E) {
    int i = blockIdx.x * 256 + threadIdx.x;
    if (i < E) {
        int p = atomicAdd(&cursor[dst[i]], 1);
        eadj[p] = src[i];
    }
}

// ---------------- edge attention + LN1 + LN2, one wave per dst node ----------
__global__ __launch_bounds__(256) void edge_attn(
    const ushort_t* __restrict__ Qb, const ushort_t* __restrict__ KV,
    const float* __restrict__ xin,
    const int* __restrict__ offs, const int* __restrict__ eadj,
    const float* __restrict__ g1, const float* __restrict__ be1,
    const float* __restrict__ g2, const float* __restrict__ be2,
    ushort_t* __restrict__ h1out, ushort_t* __restrict__ ln2out, int N)
{
    int wave = threadIdx.x >> 6, lane = threadIdx.x & 63;
    int n = blockIdx.x * 4 + wave;
    if (n >= N) return;
    int l15 = lane & 15, grp = lane >> 4;

    uint4 qp = *(const uint4*)(Qb + (size_t)n * 128 + l15 * 8);
    float q0 = u2f(qp.x << 16), q1 = u2f(qp.x & 0xffff0000u);
    float q2 = u2f(qp.y << 16), q3 = u2f(qp.y & 0xffff0000u);
    float q4 = u2f(qp.z << 16), q5 = u2f(qp.z & 0xffff0000u);
    float q6 = u2f(qp.w << 16), q7 = u2f(qp.w & 0xffff0000u);

    int s0 = offs[n], s1 = offs[n + 1];
    float a0=0.f,a1=0.f,a2=0.f,a3=0.f,a4=0.f,a5=0.f,a6=0.f,a7=0.f,z=0.f;
    for (int base = s0; base < s1; base += 64) {
        int cnt = min(s1 - base, 64);
        int ee = (base + lane < s1) ? eadj[base + lane] : 0;
        #pragma unroll 2
        for (int j = 0; j < cnt; j += 4) {
            int jj = j + grp;
            int sn = __shfl(ee, jj, 64);
            const ushort_t* kvp = KV + (size_t)sn * 256 + l15 * 16;
            uint4 kk = *(const uint4*)kvp;
            uint4 vv = *(const uint4*)(kvp + 8);
            float d0 = fmaf(q1, u2f(kk.x & 0xffff0000u), q0 * u2f(kk.x << 16));
            float d1 = fmaf(q3, u2f(kk.y & 0xffff0000u), q2 * u2f(kk.y << 16));
            float d2 = fmaf(q5, u2f(kk.z & 0xffff0000u), q4 * u2f(kk.z << 16));
            float d3 = fmaf(q7, u2f(kk.w & 0xffff0000u), q6 * u2f(kk.w << 16));
            float d = (d0 + d1) + (d2 + d3);
            d += __shfl_xor(d, 1, 64);
            float sc = fminf(5.f, fmaxf(-5.f, d * 0.25f));
            float e = (jj < cnt) ? __expf(sc) : 0.f;
            a0 = fmaf(e, u2f(vv.x << 16), a0); a1 = fmaf(e, u2f(vv.x & 0xffff0000u), a1);
            a2 = fmaf(e, u2f(vv.y << 16), a2); a3 = fmaf(e, u2f(vv.y & 0xffff0000u), a3);
            a4 = fmaf(e, u2f(vv.z << 16), a4); a5 = fmaf(e, u2f(vv.z & 0xffff0000u), a5);
            a6 = fmaf(e, u2f(vv.w << 16), a6); a7 = fmaf(e, u2f(vv.w & 0xffff0000u), a7);
            z += e;
        }
    }
    a0 += __shfl_xor(a0, 16, 64); a0 += __shfl_xor(a0, 32, 64);
    a1 += __shfl_xor(a1, 16, 64); a1 += __shfl_xor(a1, 32, 64);
    a2 += __shfl_xor(a2, 16, 64); a2 += __shfl_xor(a2, 32, 64);
    a3 += __shfl_xor(a3, 16, 64); a3 += __shfl_xor(a3, 32, 64);
    a4 += __shfl_xor(a4, 16, 64); a4 += __shfl_xor(a4, 32, 64);
    a5 += __shfl_xor(a5, 16, 64); a5 += __shfl_xor(a5, 32, 64);
    a6 += __shfl_xor(a6, 16, 64); a6 += __shfl_xor(a6, 32, 64);
    a7 += __shfl_xor(a7, 16, 64); a7 += __shfl_xor(a7, 32, 64);
    z  += __shfl_xor(z, 16, 64);  z  += __shfl_xor(z, 32, 64);
    float inv = 1.f / (z + 1e-3f);

    const float* xr = xin + (size_t)n * 128 + l15 * 8;
    float4 xa = *(const float4*)xr;
    float4 xb = *(const float4*)(xr + 4);
    float t0 = xa.x + a0 * inv, t1 = xa.y + a1 * inv;
    float t2 = xa.z + a2 * inv, t3 = xa.w + a3 * inv;
    float t4 = xb.x + a4 * inv, t5 = xb.y + a5 * inv;
    float t6 = xb.z + a6 * inv, t7 = xb.w + a7 * inv;

    float s  = t0 + t1 + t2 + t3 + t4 + t5 + t6 + t7;
    float s2 = t0*t0 + t1*t1 + t2*t2 + t3*t3 + t4*t4 + t5*t5 + t6*t6 + t7*t7;
    for (int m = 1; m < 16; m <<= 1) { s += __shfl_xor(s, m, 64); s2 += __shfl_xor(s2, m, 64); }
    float mu = s * (1.f / 128.f);
    float var = s2 * (1.f / 128.f) - mu * mu;
    float rstd = rsqrtf(var + 1e-5f);

    const float* g1r = g1 + l15 * 8;
    const float* b1r = be1 + l15 * 8;
    float4 ga = *(const float4*)g1r, gb = *(const float4*)(g1r + 4);
    float4 ba = *(const float4*)b1r, bb = *(const float4*)(b1r + 4);
    float h0 = (t0 - mu) * rstd * ga.x + ba.x;
    float h1 = (t1 - mu) * rstd * ga.y + ba.y;
    float h2 = (t2 - mu) * rstd * ga.z + ba.z;
    float h3 = (t3 - mu) * rstd * ga.w + ba.w;
    float h4 = (t4 - mu) * rstd * gb.x + bb.x;
    float h5 = (t5 - mu) * rstd * gb.y + bb.y;
    float h6 = (t6 - mu) * rstd * gb.z + bb.z;
    float h7 = (t7 - mu) * rstd * gb.w + bb.w;
    if (grp == 0) {
        uint4 pk;
        pk.x = (unsigned)f2bf(h0) | ((unsigned)f2bf(h1) << 16);
        pk.y = (unsigned)f2bf(h2) | ((unsigned)f2bf(h3) << 16);
        pk.z = (unsigned)f2bf(h4) | ((unsigned)f2bf(h5) << 16);
        pk.w = (unsigned)f2bf(h6) | ((unsigned)f2bf(h7) << 16);
        *(uint4*)(h1out + (size_t)n * 128 + l15 * 8) = pk;
    }

    s  = h0 + h1 + h2 + h3 + h4 + h5 + h6 + h7;
    s2 = h0*h0 + h1*h1 + h2*h2 + h3*h3 + h4*h4 + h5*h5 + h6*h6 + h7*h7;
    for (int m = 1; m < 16; m <<= 1) { s += __shfl_xor(s, m, 64); s2 += __shfl_xor(s2, m, 64); }
    float mu2 = s * (1.f / 128.f);
    float var2 = s2 * (1.f / 128.f) - mu2 * mu2;
    float rstd2 = rsqrtf(var2 + 1e-5f);

    const float* g2r = g2 + l15 * 8;
    const float* b2r = be2 + l15 * 8;
    float4 gc = *(const float4*)g2r, gd = *(const float4*)(g2r + 4);
    float4 bc = *(const float4*)b2r, bd = *(const float4*)(b2r + 4);
    float l0 = (h0 - mu2) * rstd2 * gc.x + bc.x;
    float l1 = (h1 - mu2) * rstd2 * gc.y + bc.y;
    float l2 = (h2 - mu2) * rstd2 * gc.z + bc.z;
    float l3 = (h3 - mu2) * rstd2 * gc.w + bc.w;
    float l4 = (h4 - mu2) * rstd2 * gd.x + bd.x;
    float l5 = (h5 - mu2) * rstd2 * gd.y + bd.y;
    float l6 = (h6 - mu2) * rstd2 * gd.z + bd.z;
    float l7 = (h7 - mu2) * rstd2 * gd.w + bd.w;
    if (grp == 1) {
        uint4 pk;
        pk.x = (unsigned)f2bf(l0) | ((unsigned)f2bf(l1) << 16);
        pk.y = (unsigned)f2bf(l2) | ((unsigned)f2bf(l3) << 16);
        pk.z = (unsigned)f2bf(l4) | ((unsigned)f2bf(l5) << 16);
        pk.w = (unsigned)f2bf(l6) | ((unsigned)f2bf(l7) << 16);
        *(uint4*)(ln2out + (size_t)n * 128 + l15 * 8) = pk;
    }
}

// ------ output GEMM: A in LDS, B swizzled-direct, coalesced f32 epilogue -----
// grid (rows, 2): snBase = blockIdx.y*4 (64-col half).
__global__ __launch_bounds__(256) void gemm_o(
    const ushort_t* __restrict__ X, const ushort_t* __restrict__ Wsw,
    const float* __restrict__ bo, const ushort_t* __restrict__ h1in,
    float* __restrict__ Out, int M)
{
    __shared__ ushort_t As[64 * 136];   // reused as float Cs[64][68] in epilogue
    int tid = threadIdx.x;
    int rowBase = blockIdx.x * 64;
    int snBase = blockIdx.y * 4;
    int colBase = snBase * 16;

    int r = tid >> 4;
    int c = (tid & 15) * 8;
    for (int rr = 0; rr < 64; rr += 16) {
        int row = rowBase + rr + r;
        int rc = (row < M) ? row : (M - 1);
        short8 v = *(const short8*)(X + (size_t)rc * 128 + c);
        *(short8*)&As[(rr + r) * 136 + c] = v;
    }
    __syncthreads();

    int lane = tid & 63, wave = tid >> 6;
    int wm = wave * 16;
    int l15 = lane & 15, quad = lane >> 4;
    floatx4 acc[4] = {};
    for (int kb = 0; kb < 4; kb++) {
        short8 a = *(const short8*)&As[(wm + l15) * 136 + kb * 32 + quad * 8];
        for (int s = 0; s < 4; s++) {
            short8 b = *(const short8*)(Wsw + (size_t)((snBase + s) * 4 + kb) * 512 + lane * 8);
            acc[s] = __builtin_amdgcn_mfma_f32_16x16x32_bf16(a, b, acc[s], 0, 0, 0);
        }
    }

    // stage relu(C+bias) as f32 into As reinterpreted (wave-private rows)
    float* Cs = (float*)As;   // stride 68 floats = 136 ushorts per row
    for (int s = 0; s < 4; s++) {
        int cl = s * 16 + l15;
        float bia = bo[colBase + cl];
        for (int rr2 = 0; rr2 < 4; rr2++) {
            int rl = wm + quad * 4 + rr2;
            Cs[rl * 68 + cl] = fmaxf(acc[s][rr2] + bia, 0.f);
        }
    }
    // coalesced write-out: 4 iters x 64 lanes x 16B f32 + coalesced h1 read
    for (int it = 0; it < 4; it++) {
        int idx = it * 64 + lane;
        int rl = idx >> 4;               // 0..15
        int c4 = (idx & 15) * 4;         // col offset (f32 x4)
        int row = rowBase + wm + rl;
        if (row < M) {
            float4 v = *(const float4*)&Cs[(wm + rl) * 68 + c4];
            uint2 hp = *(const uint2*)(h1in + (size_t)row * 128 + colBase + c4);
            v.x += u2f(hp.x << 16);
            v.y += u2f(hp.x & 0xffff0000u);
            v.z += u2f(hp.y << 16);
            v.w += u2f(hp.y & 0xffff0000u);
            *(float4*)(Out + (size_t)row * 128 + colBase + c4) = v;
        }
    }
}

extern "C" void kernel_launch(void* const* d_in, const int* in_sizes, int n_in,
                              void* d_out, int out_size, void* d_ws, size_t ws_size,
                              hipStream_t stream) {
    const int D = 128;
    const int N = in_sizes[0] / D;
    const int E = in_sizes[1];

    const float* x   = (const float*)d_in[0];
    const int*   src = (const int*)d_in[1];
    const int*   dst = (const int*)d_in[2];
    const float* Wq  = (const float*)d_in[3];
    const float* bq  = (const float*)d_in[4];
    const float* Wk  = (const float*)d_in[5];
    const float* bk  = (const float*)d_in[6];
    const float* Wv  = (const float*)d_in[7];
    const float* bv  = (const float*)d_in[8];
    const float* Wo  = (const float*)d_in[9];
    const float* bo  = (const float*)d_in[10];
    const float* g1  = (const float*)d_in[11];
    const float* be1 = (const float*)d_in[12];
    const float* g2  = (const float*)d_in[13];
    const float* be2 = (const float*)d_in[14];

    char* ws = (char*)d_ws;
    size_t o = 0;
    auto alloc = [&](size_t b) { o = (o + 255) & ~(size_t)255; size_t r = o; o += b; return r; };
    ushort_t* Qb   = (ushort_t*)(ws + alloc((size_t)N * D * 2));
    ushort_t* KVb  = (ushort_t*)(ws + alloc((size_t)N * D * 4));   // interleaved K,V (8-granular)
    ushort_t* ln2  = (ushort_t*)(ws + alloc((size_t)N * D * 2));
    ushort_t* h1   = (ushort_t*)(ws + alloc((size_t)N * D * 2));   // bf16
    ushort_t* Wt   = (ushort_t*)(ws + alloc((size_t)4 * 128 * 128 * 2));  // swizzled
    int*      deg  = (int*)(ws + alloc((size_t)N * 4));
    int*      offs = (int*)(ws + alloc((size_t)(N + 1) * 4));
    int*      cur  = (int*)(ws + alloc((size_t)N * 4));
    int*      bsum = (int*)(ws + alloc((size_t)256 * 4));
    int*      eadj = (int*)(ws + alloc((size_t)E * 4));

    int nScanBlocks = (N + 255) / 256;
    int nEdgeBlocks = (E + 255) / 256;
    int nRowTiles = (N + 63) / 64;

    hipMemsetAsync(deg, 0, (size_t)N * 4, stream);
    transpose_swz<<<dim3(8, 4), 256, 0, stream>>>(Wq, Wk, Wv, Wo, Wt);
    gemm_qkv<<<dim3(nRowTiles, 3), 256, 0, stream>>>(x, Wt, bq, bk, bv, Qb, KVb, N, dst, deg, E);
    k_scan_blocks<<<nScanBlocks, 256, 0, stream>>>(deg, offs, bsum, N);
    k_add_base<<<nScanBlocks, 256, 0, stream>>>(offs, cur, bsum, nScanBlocks, N, E);
    k_scatter<<<nEdgeBlocks, 256, 0, stream>>>(src, dst, cur, eadj, E);
    edge_attn<<<(N + 3) / 4, 256, 0, stream>>>(Qb, KVb, x, offs, eadj, g1, be1, g2, be2, h1, ln2, N);
    gemm_o<<<dim3(nRowTiles, 2), 256, 0, stream>>>(ln2, Wt + 3 * 128 * 128, bo, h1, (float*)d_out, N);
}